// Round 6
// baseline (24572.610 us; speedup 1.0000x reference)
//
#include <hip/hip_runtime.h>
#include <hip/hip_cooperative_groups.h>
#include <cmath>

namespace cg = cooperative_groups;

constexpr int kB = 32, kS = 32, kE = 512, kH = 8, kV = 10000, kNB = 4;
constexpr int kQ = 3 * kE;  // 1536
constexpr int ROWS = 4;     // rows per tail chunk
constexpr int NBLK = 256;   // cooperative grid size (1 block/CU)

// ---------------- device scratch ----------------
__device__ float g_w[kB * kS];
__device__ float g_pe[kS * kE];
__device__ float g_Y[kB * kS * kE];
__device__ float g_qkvbuf[kNB][kB * kS * kQ];
__device__ float g_actb[kNB][kB * kS * kE];
__device__ float g_logits[kB * kV];
__device__ float g_U[kNB * kE * kH];
__device__ float g_a0[kNB * kH];
__device__ float g_G[kNB * kH * kE];
__device__ float g_c0[kNB * kE];

// ---------------- setup kernels (unchanged, verified) ----------------
__global__ void onehot_k(float* __restrict__ out) {
    int i = blockIdx.x * 256 + threadIdx.x;
    if (i >= kB * kV) return;
    int b = i / kV, v = i - b * kV;
    out[(size_t)b * kS * kV + v] = (v == 0) ? 1.f : 0.f;
}

__global__ void pe_k(float* __restrict__ pe) {
    int i = blockIdx.x * 256 + threadIdx.x;  // < kS*kE
    int s = i >> 9, e = i & 511;
    int base = e & ~1;
    float div = expf((float)base * (-logf(10000.f) / (float)kE));
    float ang = (float)s * div;
    pe[i] = (e & 1) ? cosf(ang) : sinf(ang);
}

__global__ void compute_w_k(const float* __restrict__ noise, const float* __restrict__ W_in,
                            const float* __restrict__ b_in, float* __restrict__ w) {
    __shared__ float X[kB * kS], T[kB * kS];
    int tid = threadIdx.x;  // 1024
    X[tid] = noise[tid];
    __syncthreads();
    int r = tid >> 5, c = tid & 31;
    float acc = b_in[c];
    for (int k = 0; k < 32; ++k) acc = fmaf(X[r * 32 + k], W_in[k * 32 + c], acc);
    T[tid] = acc;
    __syncthreads();
    acc = b_in[32 + c];
    for (int k = 0; k < 32; ++k) acc = fmaf(T[r * 32 + k], W_in[1024 + k * 32 + c], acc);
    w[tid] = acc;
}

__global__ __launch_bounds__(256) void initY_k(const float* __restrict__ emb,
                                               const float* __restrict__ pe,
                                               float* __restrict__ Y,
                                               const float* __restrict__ Wq0,
                                               const float* __restrict__ bq0,
                                               float* __restrict__ qkv0) {
    __shared__ float ys[kE];
    int b = blockIdx.x, tid = threadIdx.x;
    for (int j = tid; j < kE; j += 256) {
        float v = emb[j] + pe[j];
        Y[(size_t)(b * kS) * kE + j] = v;
        ys[j] = v;
    }
    __syncthreads();
#pragma unroll
    for (int m = 0; m < 6; ++m) {
        int j = tid + 256 * m;
        const float* Wc = Wq0 + (size_t)(j >> 9) * (kE * kE) + (j & 511);
        float acc = bq0[j];
        for (int k = 0; k < kE; ++k) acc = fmaf(ys[k], Wc[(size_t)k * kE], acc);
        qkv0[(size_t)(b * kS) * kQ + j] = acc;
    }
}

__global__ __launch_bounds__(256) void precross_k(const float* __restrict__ Wca,
                                                  const float* __restrict__ bca,
                                                  float* __restrict__ U, float* __restrict__ a0,
                                                  float* __restrict__ G, float* __restrict__ c0) {
    int n = blockIdx.x;
    const float* Wq = Wca + (size_t)n * 4 * kE * kE;
    const float* Wk = Wq + kE * kE;
    const float* Wv = Wk + kE * kE;
    const float* Wo = Wv + kE * kE;
    const float* bq = bca + n * 4 * kE;
    const float* bv = bq + 2 * kE;
    const float* bo = bq + 3 * kE;
    __shared__ float ck[kE], cv[kE];
    int tid = threadIdx.x;
    for (int j = tid; j < kE; j += 256) {
        float s1 = 0.f, s2 = 0.f;
        for (int e = 0; e < kE; ++e) { s1 += Wk[e * kE + j]; s2 += Wv[e * kE + j]; }
        ck[j] = s1; cv[j] = s2;
    }
    __syncthreads();
    for (int p = tid; p < kE * kH; p += 256) {
        int e = p >> 3, h = p & 7;
        float acc = 0.f;
        for (int d = 0; d < 64; ++d) acc = fmaf(Wq[e * kE + h * 64 + d], ck[h * 64 + d], acc);
        U[n * kE * kH + p] = acc;
    }
    if (tid < kH) {
        float acc = 0.f;
        for (int d = 0; d < 64; ++d) acc = fmaf(bq[tid * 64 + d], ck[tid * 64 + d], acc);
        a0[n * kH + tid] = acc;
    }
    for (int p = tid; p < kH * kE; p += 256) {
        int h = p >> 9, j = p & 511;
        float acc = 0.f;
        for (int d = 0; d < 64; ++d) acc = fmaf(cv[h * 64 + d], Wo[(h * 64 + d) * kE + j], acc);
        G[n * kH * kE + p] = acc;
    }
    for (int j = tid; j < kE; j += 256) {
        float acc = bo[j];
        for (int e = 0; e < kE; ++e) acc = fmaf(bv[e], Wo[e * kE + j], acc);
        c0[n * kE + j] = acc;
    }
}

// ---------------- 512-thread helpers (math order identical to R5) ----------------
__device__ __forceinline__ void rowsum4_512(float v[ROWS], float (*red)[ROWS], float out[ROWS]) {
    int lane = threadIdx.x & 63, w = threadIdx.x >> 6;
#pragma unroll
    for (int i = 0; i < ROWS; ++i) {
        float s = v[i];
#pragma unroll
        for (int o = 32; o > 0; o >>= 1) s += __shfl_xor(s, o);
        v[i] = s;
    }
    if (lane == 0) {
#pragma unroll
        for (int i = 0; i < ROWS; ++i) red[w][i] = v[i];
    }
    __syncthreads();
#pragma unroll
    for (int i = 0; i < ROWS; ++i) {
        float s = 0.f;
#pragma unroll
        for (int w2 = 0; w2 < 8; ++w2) s += red[w2][i];
        out[i] = s;
    }
    __syncthreads();
}

__device__ __forceinline__ void ln4_512(float val[ROWS], const float* __restrict__ g,
                                        const float* __restrict__ bb, float (*red)[ROWS], int j) {
    float s[ROWS], mean[ROWS], var[ROWS];
#pragma unroll
    for (int i = 0; i < ROWS; ++i) s[i] = val[i];
    rowsum4_512(s, red, mean);
#pragma unroll
    for (int i = 0; i < ROWS; ++i) {
        mean[i] *= (1.f / (float)kE);
        val[i] -= mean[i];
        s[i] = val[i] * val[i];
    }
    rowsum4_512(s, red, var);
    float gj = g[j], bj = bb[j];
#pragma unroll
    for (int i = 0; i < ROWS; ++i) {
        float rstd = rsqrtf(var[i] * (1.f / (float)kE) + 1e-5f);
        val[i] = gj * val[i] * rstd + bj;
    }
}

// GEMM phase: out[i][j] = sum_k in[i][k]*W[k][j]; 4-way k-split + ordered LDS reduce.
__device__ __forceinline__ void gemm_phase(const float (*in)[kE], const float* __restrict__ W,
                                           float (*out)[kE], int kg, int jt) {
    float acc[ROWS][4];
#pragma unroll
    for (int i = 0; i < ROWS; ++i)
#pragma unroll
        for (int c = 0; c < 4; ++c) acc[i][c] = 0.f;
    const int kbase = kg * 128;
    const int j4 = jt * 4;
#pragma unroll 4
    for (int kk = 0; kk < 128; kk += 4) {
        const float4 wv0 = *(const float4*)(W + (size_t)(kbase + kk + 0) * kE + j4);
        const float4 wv1 = *(const float4*)(W + (size_t)(kbase + kk + 1) * kE + j4);
        const float4 wv2 = *(const float4*)(W + (size_t)(kbase + kk + 2) * kE + j4);
        const float4 wv3 = *(const float4*)(W + (size_t)(kbase + kk + 3) * kE + j4);
#pragma unroll
        for (int i = 0; i < ROWS; ++i) {
            const float4 av = *(const float4*)(&in[i][kbase + kk]);
            acc[i][0] = fmaf(av.x, wv0.x, acc[i][0]);
            acc[i][0] = fmaf(av.y, wv1.x, acc[i][0]);
            acc[i][0] = fmaf(av.z, wv2.x, acc[i][0]);
            acc[i][0] = fmaf(av.w, wv3.x, acc[i][0]);
            acc[i][1] = fmaf(av.x, wv0.y, acc[i][1]);
            acc[i][1] = fmaf(av.y, wv1.y, acc[i][1]);
            acc[i][1] = fmaf(av.z, wv2.y, acc[i][1]);
            acc[i][1] = fmaf(av.w, wv3.y, acc[i][1]);
            acc[i][2] = fmaf(av.x, wv0.z, acc[i][2]);
            acc[i][2] = fmaf(av.y, wv1.z, acc[i][2]);
            acc[i][2] = fmaf(av.z, wv2.z, acc[i][2]);
            acc[i][2] = fmaf(av.w, wv3.z, acc[i][2]);
            acc[i][3] = fmaf(av.x, wv0.w, acc[i][3]);
            acc[i][3] = fmaf(av.y, wv1.w, acc[i][3]);
            acc[i][3] = fmaf(av.z, wv2.w, acc[i][3]);
            acc[i][3] = fmaf(av.w, wv3.w, acc[i][3]);
        }
    }
    if (kg == 0) {
#pragma unroll
        for (int i = 0; i < ROWS; ++i)
            *(float4*)(&out[i][j4]) = make_float4(acc[i][0], acc[i][1], acc[i][2], acc[i][3]);
    }
    __syncthreads();
#pragma unroll
    for (int r = 1; r < 4; ++r) {
        if (kg == r) {
#pragma unroll
            for (int i = 0; i < ROWS; ++i) {
                float4 c = *(float4*)(&out[i][j4]);
                c.x += acc[i][0]; c.y += acc[i][1]; c.z += acc[i][2]; c.w += acc[i][3];
                *(float4*)(&out[i][j4]) = c;
            }
        }
        __syncthreads();
    }
}

// ---------------- persistent cooperative kernel: whole token loop ----------------
__global__ __launch_bounds__(512) void genloop_k(
    const float* w_, const float* pe_, float* Y_, float* qkvb_, float* actb_, float* lg_,
    const float* U_, const float* a0_, const float* G_, const float* c0_, float* out,
    const float* emb, const float* Wsa, const float* bsa, const float* Wff,
    const float* bff, const float* ln_g, const float* ln_b, const float* softW,
    const float* softb) {
    cg::grid_group grid = cg::this_grid();
    __shared__ __align__(16) float smem[16384];  // 64KB arena
    float (*bufA)[kE] = (float (*)[kE])smem;                 // 4x512
    float (*bufC)[kE] = (float (*)[kE])(smem + ROWS * kE);   // 4x512
    float* Us = smem + 2 * ROWS * kE;                        // 4096
    float* aux = smem + 2 * ROWS * kE + kE * kH;             // base 8192
    float (*att_s)[kS] = (float (*)[kS])aux;                 // 8x32
    float (*alp)[kH][4] = (float (*)[kH][4])(aux + 256);     // 4x8x4
    float (*om_s)[kH] = (float (*)[kH])(aux + 384);          // 4x8
    float* w_s = aux + 416;                                  // 32
    float (*red)[ROWS] = (float (*)[ROWS])(aux + 448);       // 8x4

    const int blk = blockIdx.x;
    const int tid = threadIdx.x;
    const int lane = tid & 63, wid = tid >> 6;
    const int kg = tid >> 7, jt = tid & 127;

    for (int tok = 1; tok < kS; ++tok) {
        const int t = tok;
        const int nch4 = (t + 3) >> 2;
        const int chunks = 32 * nch4;

        for (int n = 0; n < kNB; ++n) {
            const float* qkv_cur = qkvb_ + (size_t)n * (kB * kS * kQ);
            const float* in_res = (n == 0) ? Y_ : (actb_ + (size_t)(n - 1) * (kB * kS * kE));
            float* act_out = actb_ + (size_t)n * (kB * kS * kE);
            const float* Wn = Wsa + (size_t)n * 4 * kE * kE;
            const float* bn = bsa + (size_t)n * 4 * kE;
            const float* Wo = Wn + 3 * kE * kE;
            const float* bo = bn + 3 * kE;
            const float* Wf1 = Wff + (size_t)n * 2 * kE * kE;
            const float* fb1 = bff + (size_t)n * 2 * kE;
            const float* Wf2 = Wf1 + kE * kE;
            const float* fb2 = fb1 + kE;
            const float* g0 = ln_g + (size_t)(n * 3 + 0) * kE, *lb0 = ln_b + (size_t)(n * 3 + 0) * kE;
            const float* g1 = ln_g + (size_t)(n * 3 + 1) * kE, *lb1 = ln_b + (size_t)(n * 3 + 1) * kE;
            const float* g2 = ln_g + (size_t)(n * 3 + 2) * kE, *lb2 = ln_b + (size_t)(n * 3 + 2) * kE;
            const float* Um = U_ + n * kE * kH;
            const float* a0m = a0_ + n * kH;
            const float* Gm = G_ + n * kH * kE;
            const float* c0m = c0_ + n * kE;

            // ======== tail phase ========
            bool active;
            int b, c;
            if (n == 3) {  // only the chunk containing row t-1 is consumed
                active = (blk < 32);
                b = blk;
                c = (t - 1) >> 2;
            } else {
                active = (blk < chunks);
                b = blk / nch4;
                c = blk - b * nch4;
            }
            if (active) {
                const int r0 = c * ROWS;
                int rr[ROWS]; bool valid[ROWS];
#pragma unroll
                for (int i = 0; i < ROWS; ++i) {
                    int r = r0 + i;
                    valid[i] = (r < t);
                    rr[i] = valid[i] ? r : (t - 1);
                }
                for (int p = tid; p < ROWS * kE; p += 512) {
                    int i = p >> 9, d = p & 511;
                    bufA[i][d] = qkv_cur[(size_t)(b * kS + rr[i]) * kQ + d];
                }
                for (int p = tid; p < kE * kH; p += 512) Us[p] = Um[p];
                if (tid < t) w_s[tid] = w_[b * kS + tid];
                __syncthreads();

                // self-attention: wave wid -> row wid&3, heads (wid>>2)*4 ..+3
                {
                    const int i = wid & 3;
                    const int hbase = (wid >> 2) * 4;
#pragma unroll
                    for (int hh = 0; hh < 4; ++hh) {
                        const int h = hbase + hh;
                        float sc = -3.0e38f;
                        if (lane < t) {
                            const float* Kr = qkv_cur + (size_t)(b * kS + lane) * kQ + kE + h * 64;
                            float a = 0.f;
#pragma unroll
                            for (int d4 = 0; d4 < 16; ++d4) {
                                const float4 kv = *(const float4*)(Kr + d4 * 4);
                                const float4 qv = *(const float4*)(&bufA[i][h * 64 + d4 * 4]);
                                a = fmaf(qv.x, kv.x, a); a = fmaf(qv.y, kv.y, a);
                                a = fmaf(qv.z, kv.z, a); a = fmaf(qv.w, kv.w, a);
                            }
                            sc = a * 0.125f;
                        }
                        float m = sc;
#pragma unroll
                        for (int o = 32; o > 0; o >>= 1) m = fmaxf(m, __shfl_xor(m, o));
                        float e = (lane < t) ? expf(sc - m) : 0.f;
                        float ss = e;
#pragma unroll
                        for (int o = 32; o > 0; o >>= 1) ss += __shfl_xor(ss, o);
                        if (lane < t) att_s[wid][lane] = e / ss;
                        float acc = 0.f;
                        const float* Vb = qkv_cur + (size_t)(b * kS) * kQ + 2 * kE + h * 64 + lane;
                        for (int k = 0; k < t; ++k) acc = fmaf(att_s[wid][k], Vb[(size_t)k * kQ], acc);
                        bufA[i][h * 64 + lane] = acc;
                    }
                }
                __syncthreads();

                float val[ROWS], hreg[ROWS], h2reg[ROWS];

                // proj + residual + LN -> h
                gemm_phase(bufA, Wo, bufC, kg, jt);
                {
                    float btid = bo[tid];
#pragma unroll
                    for (int i = 0; i < ROWS; ++i)
                        val[i] = bufC[i][tid] + btid + in_res[(size_t)(b * kS + rr[i]) * kE + tid];
                    ln4_512(val, g0, lb0, red, tid);
#pragma unroll
                    for (int i = 0; i < ROWS; ++i) { hreg[i] = val[i]; bufA[i][tid] = val[i]; }
                }
                __syncthreads();

                // reduced cross-attn
                if (tid < 128) {
                    int i = tid >> 5, h = (tid >> 2) & 7, cs = tid & 3;
                    float a = 0.f;
                    for (int e = cs * 128; e < cs * 128 + 128; ++e)
                        a = fmaf(bufA[i][e], Us[e * kH + h], a);
                    alp[i][h][cs] = a;
                }
                __syncthreads();
                if (tid < 32) {
                    int i = tid >> 3, h = tid & 7;
                    float a = a0m[h] + alp[i][h][0] + alp[i][h][1] + alp[i][h][2] + alp[i][h][3];
                    a *= 0.125f;
                    float mm = -3.0e38f;
                    for (int s = 0; s < t; ++s) mm = fmaxf(mm, a * w_s[s]);
                    float se = 0.f, sw = 0.f;
                    for (int s = 0; s < t; ++s) {
                        float ex = expf(a * w_s[s] - mm);
                        se += ex;
                        sw = fmaf(ex, w_s[s], sw);
                    }
                    om_s[i][h] = sw / se;
                }
                __syncthreads();

                // crossout + residual(h) + LN -> h2
                {
                    float ctid = c0m[tid];
#pragma unroll
                    for (int i = 0; i < ROWS; ++i) {
                        float v = ctid + hreg[i];
#pragma unroll
                        for (int h = 0; h < kH; ++h) v = fmaf(om_s[i][h], Gm[h * kE + tid], v);
                        val[i] = v;
                    }
                    ln4_512(val, g1, lb1, red, tid);
#pragma unroll
                    for (int i = 0; i < ROWS; ++i) { h2reg[i] = val[i]; bufA[i][tid] = val[i]; }
                }
                __syncthreads();

                // FF1 + relu
                gemm_phase(bufA, Wf1, bufC, kg, jt);
                {
                    float btid = fb1[tid];
#pragma unroll
                    for (int i = 0; i < ROWS; ++i) val[i] = fmaxf(bufC[i][tid] + btid, 0.f);
#pragma unroll
                    for (int i = 0; i < ROWS; ++i) bufA[i][tid] = val[i];
                }
                __syncthreads();

                // FF2 + residual(h2) + LN -> act_out
                gemm_phase(bufA, Wf2, bufC, kg, jt);
                {
                    float btid = fb2[tid];
#pragma unroll
                    for (int i = 0; i < ROWS; ++i) val[i] = bufC[i][tid] + btid + h2reg[i];
                    ln4_512(val, g2, lb2, red, tid);
#pragma unroll
                    for (int i = 0; i < ROWS; ++i)
                        if (valid[i]) act_out[(size_t)(b * kS + r0 + i) * kE + tid] = val[i];
                }
            }
            grid.sync();

            // ======== QKV projection phase for next decoder block ========
            if (n < 3) {
                const float* Wqn = Wsa + (size_t)(n + 1) * 4 * kE * kE;
                const float* bqn = bsa + (size_t)(n + 1) * 4 * kE;
                float* qnext = qkvb_ + (size_t)(n + 1) * (kB * kS * kQ);
                const int tasks = chunks * 3;
                for (int tk = blk; tk < tasks; tk += NBLK) {
                    int slab = tk / chunks;
                    int chunk = tk - slab * chunks;
                    int bb = chunk / nch4;
                    int cc = chunk - bb * nch4;
                    int r0 = cc * ROWS;
                    int rrq[ROWS]; bool vq[ROWS];
#pragma unroll
                    for (int i = 0; i < ROWS; ++i) {
                        int r = r0 + i;
                        vq[i] = (r < t);
                        rrq[i] = vq[i] ? r : (t - 1);
                    }
                    for (int p = tid; p < ROWS * kE; p += 512) {
                        int i = p >> 9, d = p & 511;
                        bufA[i][d] = act_out[(size_t)(bb * kS + rrq[i]) * kE + d];
                    }
                    __syncthreads();
                    gemm_phase(bufA, Wqn + (size_t)slab * kE * kE, bufC, kg, jt);
                    float bj = bqn[slab * kE + tid];
#pragma unroll
                    for (int i = 0; i < ROWS; ++i)
                        if (vq[i])
                            qnext[(size_t)(bb * kS + r0 + i) * kQ + slab * kE + tid] =
                                bufC[i][tid] + bj;
                    __syncthreads();  // fence bufC reads vs next task's writes
                }
                grid.sync();
            }
        }

        // ======== logits phase (157 blocks x 64 cols; two 16-batch halves) ========
        if (blk < 157) {
            const float* ab3 = actb_ + (size_t)3 * (kB * kS * kE);
            const int tx = tid & 63, ty = tid >> 6;  // ty 0..7
            const int jcol = blk * 64 + tx;
            const int jc = (jcol < kV) ? jcol : (kV - 1);
            for (int half = 0; half < 2; ++half) {
                float* xs = smem;  // [16][512]
                for (int p = tid; p < 16 * kE; p += 512) {
                    int bb2 = p >> 9, k = p & 511;
                    xs[p] = ab3[(size_t)((half * 16 + bb2) * kS + (t - 1)) * kE + k];
                }
                __syncthreads();
                const int b0 = ty * 2, b1 = b0 + 1;
                float acc0 = softb[jc], acc1 = softb[jc];
#pragma unroll 8
                for (int k = 0; k < kE; ++k) {
                    float wv = softW[(size_t)k * kV + jc];
                    acc0 = fmaf(xs[b0 * kE + k], wv, acc0);
                    acc1 = fmaf(xs[b1 * kE + k], wv, acc1);
                }
                if (jcol < kV) {
                    lg_[(size_t)(half * 16 + b0) * kV + jcol] = acc0;
                    lg_[(size_t)(half * 16 + b1) * kV + jcol] = acc1;
                }
                __syncthreads();
            }
        }
        grid.sync();

        // ======== softmax + argmax + probs + Y row (32 blocks) ========
        if (blk < 32) {
            float* redf = smem;
            int* redi = (int*)(smem + 16);
            const float* lg = lg_ + (size_t)blk * kV;
            float m = -3.4e38f;
            int mi = 0;
            for (int j = tid; j < kV; j += 512) {
                float v = lg[j];
                if (v > m) { m = v; mi = j; }
            }
#pragma unroll
            for (int o = 32; o > 0; o >>= 1) {
                float m2 = __shfl_xor(m, o);
                int i2 = __shfl_xor(mi, o);
                if (m2 > m || (m2 == m && i2 < mi)) { m = m2; mi = i2; }
            }
            if (lane == 0) { redf[wid] = m; redi[wid] = mi; }
            __syncthreads();
            m = redf[0]; mi = redi[0];
#pragma unroll
            for (int w2 = 1; w2 < 8; ++w2)
                if (redf[w2] > m || (redf[w2] == m && redi[w2] < mi)) { m = redf[w2]; mi = redi[w2]; }
            __syncthreads();
            float ssum = 0.f;
            for (int j = tid; j < kV; j += 512) ssum += expf(lg[j] - m);
#pragma unroll
            for (int o = 32; o > 0; o >>= 1) ssum += __shfl_xor(ssum, o);
            if (lane == 0) redf[wid] = ssum;
            __syncthreads();
            ssum = 0.f;
#pragma unroll
            for (int w2 = 0; w2 < 8; ++w2) ssum += redf[w2];
            float inv = 1.f / ssum;
            float* orow = out + ((size_t)blk * kS + tok) * kV;
            for (int j = tid; j < kV; j += 512) orow[j] = expf(lg[j] - m) * inv;
            const float* erow = emb + (size_t)mi * kE;
            const float* pet = pe_ + (size_t)tok * kE;
            float* yrow = Y_ + (size_t)(blk * kS + tok) * kE;
            for (int j = tid; j < kE; j += 512) yrow[j] = erow[j] + pet[j];
        }
        grid.sync();

        // ======== qkv0 row for the new token (24 blocks x 64 cols) ========
        if (blk < 24) {
            float (*ys)[kE] = (float (*)[kE])smem;  // 32x512 = 64KB
            for (int p = tid; p < kB * kE; p += 512) {
                int bb2 = p >> 9, k = p & 511;
                ys[bb2][k] = Y_[(size_t)(bb2 * kS + tok) * kE + k];
            }
            __syncthreads();
            const int tx = tid & 63, ty = tid >> 6;  // ty 0..7 -> batches 4ty..4ty+3
            const int j = blk * 64 + tx;
            const float* Wc = Wsa + (size_t)(j >> 9) * (kE * kE) + (j & 511);
            float bj = bsa[j];
            float acc[4];
#pragma unroll
            for (int i = 0; i < 4; ++i) acc[i] = bj;
#pragma unroll 2
            for (int k = 0; k < kE; k += 4) {
                float w0 = Wc[(size_t)(k + 0) * kE];
                float w1 = Wc[(size_t)(k + 1) * kE];
                float w2 = Wc[(size_t)(k + 2) * kE];
                float w3 = Wc[(size_t)(k + 3) * kE];
#pragma unroll
                for (int i = 0; i < 4; ++i) {
                    const float4 yv = *(const float4*)(&ys[ty * 4 + i][k]);
                    float a = acc[i];
                    a = fmaf(yv.x, w0, a);
                    a = fmaf(yv.y, w1, a);
                    a = fmaf(yv.z, w2, a);
                    a = fmaf(yv.w, w3, a);
                    acc[i] = a;
                }
            }
#pragma unroll
            for (int i = 0; i < 4; ++i)
                qkvb_[(size_t)((ty * 4 + i) * kS + tok) * kQ + j] = acc[i];
        }
        grid.sync();
    }
}

// ---------------- host ----------------
extern "C" void kernel_launch(void* const* d_in, const int* in_sizes, int n_in, void* d_out,
                              int out_size, void* d_ws, size_t ws_size, hipStream_t stream) {
    const float* noise = (const float*)d_in[0];
    const float* W_in = (const float*)d_in[1];
    const float* b_in = (const float*)d_in[2];
    const float* emb = (const float*)d_in[3];
    const float* Wsa = (const float*)d_in[4];
    const float* bsa = (const float*)d_in[5];
    const float* Wca = (const float*)d_in[6];
    const float* bca = (const float*)d_in[7];
    const float* Wff = (const float*)d_in[8];
    const float* bff = (const float*)d_in[9];
    const float* ln_g = (const float*)d_in[10];
    const float* ln_b = (const float*)d_in[11];
    const float* softW = (const float*)d_in[12];
    const float* softb = (const float*)d_in[13];
    float* out = (float*)d_out;
    (void)d_ws; (void)ws_size; (void)in_sizes; (void)n_in; (void)out_size;

    float *w_, *pe_, *Y_, *qkvb_, *actb_, *lg_, *U_, *a0_, *G_, *c0_;
    hipGetSymbolAddress((void**)&w_, HIP_SYMBOL(g_w));
    hipGetSymbolAddress((void**)&pe_, HIP_SYMBOL(g_pe));
    hipGetSymbolAddress((void**)&Y_, HIP_SYMBOL(g_Y));
    hipGetSymbolAddress((void**)&qkvb_, HIP_SYMBOL(g_qkvbuf));
    hipGetSymbolAddress((void**)&actb_, HIP_SYMBOL(g_actb));
    hipGetSymbolAddress((void**)&lg_, HIP_SYMBOL(g_logits));
    hipGetSymbolAddress((void**)&U_, HIP_SYMBOL(g_U));
    hipGetSymbolAddress((void**)&a0_, HIP_SYMBOL(g_a0));
    hipGetSymbolAddress((void**)&G_, HIP_SYMBOL(g_G));
    hipGetSymbolAddress((void**)&c0_, HIP_SYMBOL(g_c0));

    dim3 blk(256);
    hipLaunchKernelGGL(onehot_k, dim3((kB * kV + 255) / 256), blk, 0, stream, out);
    hipLaunchKernelGGL(pe_k, dim3(kS * kE / 256), blk, 0, stream, pe_);
    hipLaunchKernelGGL(compute_w_k, dim3(1), dim3(1024), 0, stream, noise, W_in, b_in, w_);
    hipLaunchKernelGGL(initY_k, dim3(kB), blk, 0, stream, emb, pe_, Y_, Wsa, bsa, qkvb_);
    hipLaunchKernelGGL(precross_k, dim3(kNB), blk, 0, stream, Wca, bca, U_, a0_, G_, c0_);

    void* kargs[] = {&w_, &pe_, &Y_, &qkvb_, &actb_, &lg_, &U_, &a0_, &G_, &c0_,
                     &out, &emb, &Wsa, &bsa, &Wff, &bff, &ln_g, &ln_b, &softW, &softb};
    hipLaunchCooperativeKernel((const void*)genloop_k, dim3(NBLK), dim3(512), kargs, 0, stream);
}